// Round 2
// baseline (3477.328 us; speedup 1.0000x reference)
//
#include <hip/hip_runtime.h>

#define DEV __device__ __forceinline__

typedef unsigned short u16;
using bf16x8 = __attribute__((ext_vector_type(8))) __bf16;
using f32x4  = __attribute__((ext_vector_type(4))) float;

DEV u16 f2bf(float f){
  unsigned u = __float_as_uint(f);
  u += 0x7fffu + ((u >> 16) & 1u);   // round-to-nearest-even
  return (u16)(u >> 16);
}
DEV float sigf(float x){ return 1.f / (1.f + __expf(-x)); }
DEV float tanh_(float x){ return 2.f / (1.f + __expf(-2.f*x)) - 1.f; }

DEV void async16(const u16* g, u16* l){
  __builtin_amdgcn_global_load_lds(
      (const __attribute__((address_space(1))) unsigned int*)g,
      (__attribute__((address_space(3))) unsigned int*)l, 16, 0, 0);
}

DEV float cellf(float gi, float gf, float gg, float go, float& c){
  float i = sigf(gi), f = sigf(gf), g = tanh_(gg), o = sigf(go);
  c = f * c + i * g;
  return o * tanh_(c);
}

// ---------------- BatchNorm prep ----------------
__global__ void bn_stats(const float* __restrict__ z, float* __restrict__ ps, float* __restrict__ pq){
  int bx = blockIdx.x; int rg = bx >> 2, cg = bx & 3;
  int c = cg*256 + threadIdx.x;
  float s = 0.f, q = 0.f;
  for (int r = rg*64; r < rg*64 + 64; ++r){ float v = z[r*1024 + c]; s += v; q += v*v; }
  ps[rg*1024 + c] = s; pq[rg*1024 + c] = q;
}

__global__ void bn_fin(const float* __restrict__ ps, const float* __restrict__ pq,
                       const float* __restrict__ gam, const float* __restrict__ bet,
                       float* __restrict__ sc, float* __restrict__ sh){
  int c = blockIdx.x*256 + threadIdx.x;
  float s = 0.f, q = 0.f;
  for (int rg = 0; rg < 16; ++rg){ s += ps[rg*1024 + c]; q += pq[rg*1024 + c]; }
  float mean = s * (1.f/1024.f);
  float var  = q * (1.f/1024.f) - mean*mean;
  float k = gam[c] * rsqrtf(var + 1e-5f);
  sc[c] = k; sh[c] = bet[c] - mean*k;
}

__global__ void bn_norm(const float* __restrict__ z, const float* __restrict__ sc, const float* __restrict__ sh,
                        u16* __restrict__ h0, u16* __restrict__ h1){
  int bx = blockIdx.x; int rg = bx >> 2, cg = bx & 3;
  int c = cg*256 + threadIdx.x;
  float k = sc[c], b = sh[c];
  for (int r = rg*64; r < rg*64 + 64; ++r){
    float v = z[r*1024 + c]*k + b;
    u16 hv = f2bf(v);
    h0[r*1024 + c] = hv; h1[r*1024 + c] = hv;
  }
}

// ---------------- weight convert (+gate-interleave permutation) --------------
__global__ void conv_w(const float* __restrict__ src, u16* __restrict__ dst,
                       int dstStride, int colOff, int permute){
  int c = blockIdx.x;
  int row = c;
  if (permute){ int gate = (c>>4)&3; int u = (c&15) | ((c>>6)<<4); row = (gate<<10) + u; }
  float4 v = ((const float4*)(src + (size_t)row*1024))[threadIdx.x];
  ushort4 o; o.x = f2bf(v.x); o.y = f2bf(v.y); o.z = f2bf(v.z); o.w = f2bf(v.w);
  ((ushort4*)(dst + (size_t)c*dstStride + colOff))[threadIdx.x] = o;
}

__global__ void bias_k(const float* __restrict__ bi0, const float* __restrict__ bh0,
                       const float* __restrict__ bi1, const float* __restrict__ bh1,
                       float* __restrict__ bx0, float* __restrict__ b1){
  int c = blockIdx.x*256 + threadIdx.x;
  int gate = (c>>4)&3; int u = (c&15) | ((c>>6)<<4); int r = (gate<<10) + u;
  bx0[c] = bi0[r] + bh0[r];
  b1[c]  = bi1[r] + bh1[r];
}

// ---------------- double-buffered MFMA k-loop --------------------------------
// A0/A1/Bm point at tile origin. A ld = 1024; B ld = K. nkt = K/32.
DEV void kloop(const u16* __restrict__ A0, const u16* __restrict__ A1, int kloA,
               const u16* __restrict__ Bm, int K, int nkt,
               f32x4 (&acc)[4][4], u16* sAb, u16* sBb,
               int t, int wm, int wn, int lane)
{
  const int rA = t >> 2, kp = (t & 3) * 8;

#define STAGE(buf, kt) {                                                   \
    int k0_ = (kt) << 5;                                                   \
    const u16* ap_ = A0; int kk_ = k0_ + kp;                               \
    if (k0_ >= kloA){ ap_ = A1; kk_ = k0_ - kloA + kp; }                   \
    u16* dA_ = sAb + (buf)*4096 + t*8;                                     \
    u16* dB_ = sBb + (buf)*4096 + t*8;                                     \
    async16(ap_ + (size_t)rA*1024 + kk_, dA_);                             \
    async16(ap_ + ((size_t)rA + 64)*1024 + kk_, dA_ + 2048);               \
    async16(Bm  + (size_t)rA*K + k0_ + kp, dB_);                           \
    async16(Bm  + ((size_t)rA + 64)*K + k0_ + kp, dB_ + 2048); }

  STAGE(0, 0);
  for (int kt = 0; kt < nkt; ++kt){
    const int cur = kt & 1;
    if (kt + 1 < nkt){
      STAGE(cur ^ 1, kt + 1);
      asm volatile("s_waitcnt vmcnt(4)" ::: "memory");   // cur tile landed; prefetch in flight
    } else {
      asm volatile("s_waitcnt vmcnt(0)" ::: "memory");
    }
    __builtin_amdgcn_s_barrier();
    asm volatile("" ::: "memory");
    const u16* pA = sAb + cur*4096;
    const u16* pB = sBb + cur*4096;
    bf16x8 af[4], bfr[4];
#pragma unroll
    for (int i = 0; i < 4; ++i){
      af[i]  = *(const bf16x8*)&pA[(wm*64 + i*16 + (lane & 15))*32 + (lane >> 4)*8];
      bfr[i] = *(const bf16x8*)&pB[(wn*64 + i*16 + (lane & 15))*32 + (lane >> 4)*8];
    }
#pragma unroll
    for (int i = 0; i < 4; ++i)
#pragma unroll
      for (int jj = 0; jj < 4; ++jj)
        acc[i][jj] = __builtin_amdgcn_mfma_f32_16x16x32_bf16(af[i], bfr[jj], acc[i][jj], 0, 0, 0);
    asm volatile("s_waitcnt lgkmcnt(0)" ::: "memory");    // my ds_reads done
    __builtin_amdgcn_s_barrier();                          // safe to overwrite cur
    asm volatile("" ::: "memory");
  }
#undef STAGE
}

// ---------------- persistent fused LSTM kernel -------------------------------
__global__ __launch_bounds__(256, 1)
void persist(const u16* __restrict__ Wih0p, const u16* __restrict__ Whh0p,
             const u16* __restrict__ W1p,   const u16* __restrict__ Wlinp,
             const float* __restrict__ Bx0, const float* __restrict__ B1,
             const float* __restrict__ blin,
             const float* __restrict__ z, const float* __restrict__ Sc, const float* __restrict__ Sh,
             u16* __restrict__ h0a, u16* __restrict__ h0b,
             u16* __restrict__ h1a, u16* __restrict__ h1b,
             u16* __restrict__ feats, float* __restrict__ outp, int* __restrict__ ctr)
{
  __shared__ u16 sA[2*4096];
  __shared__ u16 sB[2*4096];
  const int t = threadIdx.x, lane = t & 63;
  const int w = t >> 6, wm = w >> 1, wn = w & 1;
  // XCD swizzle: linear block id % 8 == blockIdx.x -> all 4 j-slices of one XCD share weights in its L2
  const int j = blockIdx.x*4 + (blockIdx.y & 3);
  const int g = blockIdx.y >> 2;
  const int sl = lane & 15, rq = (lane >> 4) * 4;
  const int uu = sl + ((j*2 + wn) << 4);          // hidden-unit index owned by this lane
  int* c0arr = ctr;                                // [32][8]
  int* c1arr = ctr + 256;                          // [32][8]

  f32x4 acc[4][4];

  // ---- phase P: x0proj tile into registers; c0/c1 init from f32 zn ----
#pragma unroll
  for (int i = 0; i < 4; ++i)
#pragma unroll
    for (int jj = 0; jj < 4; ++jj) acc[i][jj] = (f32x4){0.f,0.f,0.f,0.f};
  kloop(h0a + (size_t)g*128*1024, h0a + (size_t)g*128*1024, 1024,
        Wih0p + (size_t)j*128*1024, 1024, 32, acc, sA, sB, t, wm, wn, lane);

  f32x4 xin[4][4];
#pragma unroll
  for (int jj = 0; jj < 4; ++jj){
    float bx = Bx0[j*128 + wn*64 + jj*16 + sl];
#pragma unroll
    for (int i = 0; i < 4; ++i){
      xin[i][jj] = acc[i][jj];
#pragma unroll
      for (int r = 0; r < 4; ++r) xin[i][jj][r] += bx;
    }
  }

  float c0v[4][4], c1v[4][4];
  {
    float k = Sc[uu], b = Sh[uu];
#pragma unroll
    for (int i = 0; i < 4; ++i){
      int rowb = g*128 + wm*64 + i*16 + rq;
#pragma unroll
      for (int r = 0; r < 4; ++r){
        float v = z[(size_t)(rowb + r)*1024 + uu]*k + b;
        c0v[i][r] = v; c1v[i][r] = v;
      }
    }
  }

  u16* h0buf[2] = {h0a, h0b};
  u16* h1buf[2] = {h1a, h1b};

  for (int s = 0; s < 32; ++s){
    u16* h0c = h0buf[s & 1];      u16* h0n = h0buf[(s + 1) & 1];
    u16* h1c = h1buf[s & 1];      u16* h1n = h1buf[(s + 1) & 1];

    // ---- GEMM0: gates0 = h0c @ Whh0^T + x0proj(+biases) ----
#pragma unroll
    for (int i = 0; i < 4; ++i)
#pragma unroll
      for (int jj = 0; jj < 4; ++jj) acc[i][jj] = xin[i][jj];
    kloop(h0c + (size_t)g*128*1024, h0c + (size_t)g*128*1024, 1024,
          Whh0p + (size_t)j*128*1024, 1024, 32, acc, sA, sB, t, wm, wn, lane);
#pragma unroll
    for (int i = 0; i < 4; ++i){
      int rowb = g*128 + wm*64 + i*16 + rq;
#pragma unroll
      for (int r = 0; r < 4; ++r){
        float h = cellf(acc[i][0][r], acc[i][1][r], acc[i][2][r], acc[i][3][r], c0v[i][r]);
        h0n[(size_t)(rowb + r)*1024 + uu] = f2bf(h);
      }
    }
    __syncthreads();                                   // drains stores (vmcnt 0)
    if (t == 0){
      __hip_atomic_fetch_add(&c0arr[s*8 + g], 1, __ATOMIC_RELEASE, __HIP_MEMORY_SCOPE_AGENT);
      long n = 0;
      while (__hip_atomic_load(&c0arr[s*8 + g], __ATOMIC_RELAXED, __HIP_MEMORY_SCOPE_AGENT) < 32){
        __builtin_amdgcn_s_sleep(1); if (++n > (1L<<26)) break;
      }
      if (s > 0){
        n = 0;
        while (__hip_atomic_load(&c1arr[(s-1)*8 + g], __ATOMIC_RELAXED, __HIP_MEMORY_SCOPE_AGENT) < 32){
          __builtin_amdgcn_s_sleep(1); if (++n > (1L<<26)) break;
        }
      }
    }
    __builtin_amdgcn_fence(__ATOMIC_ACQUIRE, "agent");  // invalidate L1/L2: see peers' h
    __syncthreads();

    // ---- GEMM1: gates1 = [h0n | h1c] @ [Wih1|Whh1]^T + b1 ----
#pragma unroll
    for (int jj = 0; jj < 4; ++jj){
      float bv = B1[j*128 + wn*64 + jj*16 + sl];
      f32x4 b4 = (f32x4){bv, bv, bv, bv};
#pragma unroll
      for (int i = 0; i < 4; ++i) acc[i][jj] = b4;
    }
    kloop(h0n + (size_t)g*128*1024, h1c + (size_t)g*128*1024, 1024,
          W1p + (size_t)j*128*2048, 2048, 64, acc, sA, sB, t, wm, wn, lane);
#pragma unroll
    for (int i = 0; i < 4; ++i){
      int rowb = g*128 + wm*64 + i*16 + rq;
#pragma unroll
      for (int r = 0; r < 4; ++r){
        float h = cellf(acc[i][0][r], acc[i][1][r], acc[i][2][r], acc[i][3][r], c1v[i][r]);
        u16 hb = f2bf(h);
        int row = rowb + r;
        h1n[(size_t)row*1024 + uu] = hb;
        feats[(size_t)row*32768 + s*1024 + uu] = hb;   // (B, bar, H)
      }
    }
    __syncthreads();
    if (t == 0)
      __hip_atomic_fetch_add(&c1arr[s*8 + g], 1, __ATOMIC_RELEASE, __HIP_MEMORY_SCOPE_AGENT);
    // no wait here: next GEMM0 only needs ctr0[s] (already passed); ctr1[s] waited next iter
  }

  // ---- head: out = feats @ Wlin^T + blin (rows 4096g+128j .. +128) ----
  if (t == 0){
    long n = 0;
    while (__hip_atomic_load(&c1arr[31*8 + g], __ATOMIC_RELAXED, __HIP_MEMORY_SCOPE_AGENT) < 32){
      __builtin_amdgcn_s_sleep(1); if (++n > (1L<<26)) break;
    }
  }
  __builtin_amdgcn_fence(__ATOMIC_ACQUIRE, "agent");
  __syncthreads();

  const size_t R0 = (size_t)(4096*g + 128*j);
  for (int ct = 0; ct < 8; ++ct){
#pragma unroll
    for (int jj = 0; jj < 4; ++jj){
      float bv = blin[ct*128 + wn*64 + jj*16 + sl];
      f32x4 b4 = (f32x4){bv, bv, bv, bv};
#pragma unroll
      for (int i = 0; i < 4; ++i) acc[i][jj] = b4;
    }
    kloop(feats + R0*1024, feats + R0*1024, 1024,
          Wlinp + (size_t)ct*128*1024, 1024, 32, acc, sA, sB, t, wm, wn, lane);
#pragma unroll
    for (int jj = 0; jj < 4; ++jj){
      int col = ct*128 + wn*64 + jj*16 + sl;
#pragma unroll
      for (int i = 0; i < 4; ++i){
        size_t rowb = R0 + wm*64 + i*16 + rq;
#pragma unroll
        for (int r = 0; r < 4; ++r)
          outp[(rowb + r)*1024 + col] = acc[i][jj][r];
      }
    }
    __syncthreads();   // LDS reuse safety between head tiles
  }
}

// ---------------------------------------------------------------------------
extern "C" void kernel_launch(void* const* d_in, const int* in_sizes, int n_in,
                              void* d_out, int out_size, void* d_ws, size_t ws_size,
                              hipStream_t stream)
{
  (void)in_sizes; (void)n_in; (void)out_size; (void)ws_size;
  const float* z    = (const float*)d_in[0];
  const float* gam  = (const float*)d_in[1];
  const float* bet  = (const float*)d_in[2];
  const float* Wih0 = (const float*)d_in[3];
  const float* Whh0 = (const float*)d_in[4];
  const float* bih0 = (const float*)d_in[5];
  const float* bhh0 = (const float*)d_in[6];
  const float* Wih1 = (const float*)d_in[7];
  const float* Whh1 = (const float*)d_in[8];
  const float* bih1 = (const float*)d_in[9];
  const float* bhh1 = (const float*)d_in[10];
  const float* Wlin = (const float*)d_in[11];
  const float* blin = (const float*)d_in[12];
  float* out = (float*)d_out;

  char* p = (char*)d_ws;
  auto alloc = [&](size_t b) -> void* { void* r = (void*)p; p += (b + 255) & ~(size_t)255; return r; };
  u16*  Wih0p = (u16*)alloc((size_t)4096*1024*2);
  u16*  Whh0p = (u16*)alloc((size_t)4096*1024*2);
  u16*  W1p   = (u16*)alloc((size_t)4096*2048*2);
  u16*  Wlinp = (u16*)alloc((size_t)1024*1024*2);
  float* Bx0  = (float*)alloc(4096*4);
  float* B1   = (float*)alloc(4096*4);
  u16*  H0a   = (u16*)alloc((size_t)1024*1024*2);
  u16*  H0b   = (u16*)alloc((size_t)1024*1024*2);
  u16*  H1a   = (u16*)alloc((size_t)1024*1024*2);
  u16*  H1b   = (u16*)alloc((size_t)1024*1024*2);
  u16*  Feats = (u16*)alloc((size_t)1024*32*1024*2);
  float* PS   = (float*)alloc(16*1024*4);
  float* PQ   = (float*)alloc(16*1024*4);
  float* Sc   = (float*)alloc(1024*4);
  float* Sh   = (float*)alloc(1024*4);
  int*   Ctr  = (int*)alloc(512*4);

  hipMemsetAsync(Ctr, 0, 512*4, stream);

  bn_stats<<<64, 256, 0, stream>>>(z, PS, PQ);
  bn_fin<<<4, 256, 0, stream>>>(PS, PQ, gam, bet, Sc, Sh);
  bn_norm<<<64, 256, 0, stream>>>(z, Sc, Sh, H0a, H1a);
  conv_w<<<4096, 256, 0, stream>>>(Wih0, Wih0p, 1024, 0, 1);
  conv_w<<<4096, 256, 0, stream>>>(Whh0, Whh0p, 1024, 0, 1);
  conv_w<<<4096, 256, 0, stream>>>(Wih1, W1p, 2048, 0, 1);
  conv_w<<<4096, 256, 0, stream>>>(Whh1, W1p, 2048, 1024, 1);
  conv_w<<<1024, 256, 0, stream>>>(Wlin, Wlinp, 1024, 0, 0);
  bias_k<<<16, 256, 0, stream>>>(bih0, bhh0, bih1, bhh1, Bx0, B1);

  persist<<<dim3(8, 32), 256, 0, stream>>>(Wih0p, Whh0p, W1p, Wlinp, Bx0, B1, blin,
                                           z, Sc, Sh, H0a, H0b, H1a, H1b, Feats, out, Ctr);
}